// Round 1
// baseline (12692.099 us; speedup 1.0000x reference)
//
#include <hip/hip_runtime.h>
#include <cstdint>

typedef _Float16 f16;
typedef _Float16 f16x8 __attribute__((ext_vector_type(8)));
typedef float f32x4 __attribute__((ext_vector_type(4)));

#define DI static __device__ __forceinline__

constexpr int T = 512, H = 512, Osz = 10;
constexpr int NWG = 256, NTH = 768;      // 12 waves per WG, 1 WG/CU
constexpr int GW = 32;                   // WGs per batch-group
constexpr int GB = 8;                    // batch rows per group
constexpr int BH = 64 * H;               // elements per h-buffer parity

struct __align__(256) GSync { unsigned cnt[2]; unsigned epoch; unsigned pad[61]; };

DI float sigf(float x)   { return 1.f / (1.f + __expf(-x)); }
DI float tanhf_(float x) { return 1.f - 2.f / (__expf(2.f * x) + 1.f); }

DI f16x8 cvt8(const float* p) {
  f16x8 r;
#pragma unroll
  for (int j = 0; j < 8; ++j) r[j] = (f16)p[j];
  return r;
}

DI void group_barrier(GSync* g, unsigned idx, int tid) {
  __syncthreads();   // all waves' stores drained to L2 (waitcnt before s_barrier)
  if (tid == 0) {
    __threadfence(); // push WG stores L2 -> LLC (cross-XCD robust)
    unsigned old = __hip_atomic_fetch_add(&g->cnt[idx & 1], 1u,
                                          __ATOMIC_ACQ_REL, __HIP_MEMORY_SCOPE_AGENT);
    if (old == GW - 1) {
      __hip_atomic_store(&g->cnt[idx & 1], 0u, __ATOMIC_RELAXED, __HIP_MEMORY_SCOPE_AGENT);
      __hip_atomic_store(&g->epoch, idx + 1, __ATOMIC_RELEASE, __HIP_MEMORY_SCOPE_AGENT);
    } else {
      unsigned spins = 0;
      while (__hip_atomic_load(&g->epoch, __ATOMIC_ACQUIRE, __HIP_MEMORY_SCOPE_AGENT) < idx + 1) {
        __builtin_amdgcn_s_sleep(2);
        if (++spins > 5000u) break;  // safety: never trips when healthy
      }
    }
  }
  __syncthreads();
}

__global__ __launch_bounds__(NTH) void rnn_all(
    const float* __restrict__ x,
    const float* __restrict__ lwih, const float* __restrict__ lwhh,
    const float* __restrict__ lbih, const float* __restrict__ lbhh,
    const float* __restrict__ gwih, const float* __restrict__ gwhh,
    const float* __restrict__ gbih, const float* __restrict__ gbhh,
    const float* __restrict__ rwih, const float* __restrict__ rwhh,
    const float* __restrict__ rbih, const float* __restrict__ rbhh,
    const float* __restrict__ fcw, const float* __restrict__ fcb,
    float* __restrict__ out, char* __restrict__ ws)
{
  __shared__ float P[12][16][16];   // per-wave C fragments: [wave][n(gate-col)][m(batch)]
  __shared__ float sb[16][11];      // biases per owned column

  const int tid  = threadIdx.x;
  const int bid  = blockIdx.x;
  const int grp  = bid & 7;         // batch group (likely XCD-local)
  const int w32  = bid >> 3;        // WG index inside group: owns 16 h-columns
  const int bg0  = grp * GB;
  const int col0 = w32 * 16;
  const int w    = tid >> 6;        // wave id 0..11
  const int lane = tid & 63;
  const int ln   = lane & 15;       // A: m-row / B: n-col / D: col
  const int lk   = lane >> 4;       // K sub-block

  GSync* gs = reinterpret_cast<GSync*>(ws) + grp;
  f16* HL = reinterpret_cast<f16*>(ws + 4096);
  f16* HG = HL + 2 * BH;
  f16* HR = HG + 2 * BH;

  // ---- W fragments -> registers (persist across all 514 steps) ----
  // waves 0-3: LSTM gates i,f,g,o (K = 512 hh + 256 ih(x))
  // waves 4-6: GRU w_ih gates r,z,n (input = h_lstm, K=512)
  // waves 7-9: GRU w_hh gates r,z,n (K=512)
  // wave 10:   RNN w_hh (K=512) ; wave 11: RNN w_ih (input = h_gru, K=512)
  f16x8 Bw[24];
  if (w < 4) {
    const int row = w * 512 + col0 + ln;
    const float* ph  = lwhh + (size_t)row * 512 + lk * 8;
    const float* px2 = lwih + (size_t)row * 256 + lk * 8;
#pragma unroll
    for (int ks = 0; ks < 16; ++ks) Bw[ks] = cvt8(ph + ks * 32);
#pragma unroll
    for (int ks = 0; ks < 8;  ++ks) Bw[16 + ks] = cvt8(px2 + ks * 32);
  } else if (w < 7) {
    const int row = (w - 4) * 512 + col0 + ln;
    const float* p = gwih + (size_t)row * 512 + lk * 8;
#pragma unroll
    for (int ks = 0; ks < 16; ++ks) Bw[ks] = cvt8(p + ks * 32);
  } else if (w < 10) {
    const int row = (w - 7) * 512 + col0 + ln;
    const float* p = gwhh + (size_t)row * 512 + lk * 8;
#pragma unroll
    for (int ks = 0; ks < 16; ++ks) Bw[ks] = cvt8(p + ks * 32);
  } else if (w == 10) {
    const float* p = rwhh + (size_t)(col0 + ln) * 512 + lk * 8;
#pragma unroll
    for (int ks = 0; ks < 16; ++ks) Bw[ks] = cvt8(p + ks * 32);
  } else {
    const float* p = rwih + (size_t)(col0 + ln) * 512 + lk * 8;
#pragma unroll
    for (int ks = 0; ks < 16; ++ks) Bw[ks] = cvt8(p + ks * 32);
  }

  // ---- biases -> LDS ----
  for (int i = tid; i < 16 * 11; i += NTH) {
    int c = i / 11, j = i % 11, col = col0 + c;
    float v;
    if (j < 4)       v = lbih[j * 512 + col] + lbhh[j * 512 + col];
    else if (j < 7)  v = gbih[(j - 4) * 512 + col];
    else if (j < 10) v = gbhh[(j - 7) * 512 + col];
    else             v = rbih[col] + rbhh[col];
    sb[c][j] = v;
  }

  // ---- zero this group's h-state (both parities, 3 buffers) ----
  {
    int i = w32 * NTH + tid;           // 0..24575 over the group
    int buf = i >> 13;
    int r = i & 8191;
    int par = r >> 12;
    int bl = (r >> 9) & 7;
    int col = r & 511;
    f16* Hb = (buf == 0) ? HL : (buf == 1) ? HG : HR;
    Hb[par * BH + (bg0 + bl) * H + col] = (f16)0.f;
  }

  group_barrier(gs, 0u, tid);

  float creg = 0.f;  // LSTM cell state (combine threads, tid<128)

#pragma unroll 1
  for (int s = 0; s <= T + 1; ++s) {
    const int cur = s & 1, prev = cur ^ 1;
    const f16* HLp = HL + prev * BH;
    const f16* HGp = HG + prev * BH;
    const f16* HRp = HR + prev * BH;
    const int sc = (s < T) ? s : (T - 1);
    const int ab = bg0 + (ln & 7);     // A batch row (rows 8..15 duplicate)

    f32x4 acc = {0.f, 0.f, 0.f, 0.f};
    if (w < 4) {
      const f16* pa = HLp + (size_t)ab * H + lk * 8;
#pragma unroll
      for (int ks = 0; ks < 16; ++ks)
        acc = __builtin_amdgcn_mfma_f32_16x16x32_f16(
            *reinterpret_cast<const f16x8*>(pa + ks * 32), Bw[ks], acc, 0, 0, 0);
      const float* px = x + (size_t)ab * (T * 256) + (size_t)sc * 256 + lk * 8;
#pragma unroll
      for (int ks = 0; ks < 8; ++ks) {
        f16x8 a = cvt8(px + ks * 32);
        acc = __builtin_amdgcn_mfma_f32_16x16x32_f16(a, Bw[16 + ks], acc, 0, 0, 0);
      }
    } else {
      const f16* hsrc = (w < 10) ? ((w < 7) ? HLp : HGp) : ((w == 10) ? HRp : HGp);
      const f16* pa = hsrc + (size_t)ab * H + lk * 8;
#pragma unroll
      for (int ks = 0; ks < 16; ++ks)
        acc = __builtin_amdgcn_mfma_f32_16x16x32_f16(
            *reinterpret_cast<const f16x8*>(pa + ks * 32), Bw[ks], acc, 0, 0, 0);
    }
    *reinterpret_cast<f32x4*>(&P[w][ln][lk * 4]) = acc;
    __syncthreads();

    if (tid < 128) {  // waves 0,1: gate math in fp32
      const int cb = tid >> 4, cc = tid & 15;
      const int gb = bg0 + cb, col = col0 + cc;
      float iL = sigf(P[0][cc][cb] + sb[cc][0]);
      float fL = sigf(P[1][cc][cb] + sb[cc][1]);
      float gL = tanhf_(P[2][cc][cb] + sb[cc][2]);
      float oL = sigf(P[3][cc][cb] + sb[cc][3]);
      float cn = fL * creg + iL * gL;
      float hLv = oL * tanhf_(cn);
      float xr = P[4][cc][cb] + sb[cc][4];
      float xz = P[5][cc][cb] + sb[cc][5];
      float xn = P[6][cc][cb] + sb[cc][6];
      float hr = P[7][cc][cb] + sb[cc][7];
      float hz = P[8][cc][cb] + sb[cc][8];
      float hn = P[9][cc][cb] + sb[cc][9];
      float rg = sigf(xr + hr), zg = sigf(xz + hz);
      float ng = tanhf_(xn + rg * hn);
      float hgprev = (float)HGp[gb * H + col];
      float hGv = (1.f - zg) * ng + zg * hgprev;
      float hRv = tanhf_(P[10][cc][cb] + P[11][cc][cb] + sb[cc][10]);
      if (s < T)            { creg = cn; HL[cur * BH + gb * H + col] = (f16)hLv; }
      if (s >= 1 && s <= T) HG[cur * BH + gb * H + col] = (f16)hGv;
      if (s >= 2)           HR[cur * BH + gb * H + col] = (f16)hRv;
    }
    group_barrier(gs, (unsigned)(s + 1), tid);
  }

  // ---- FC epilogue: one WG per group, h_rnn(T-1) lives in parity 1 ----
  if (w32 == 0 && tid < 640) {
    const f16* hlast = HR + BH;
    int bo = tid >> 3, kq = tid & 7;
    int bl = bo / 10, o = bo % 10;
    const f16* ph = hlast + (size_t)(bg0 + bl) * H + kq * 64;
    const float* pw = fcw + (size_t)o * H + kq * 64;
    float a = 0.f;
#pragma unroll
    for (int k = 0; k < 64; ++k) a += (float)ph[k] * pw[k];
    a += __shfl_xor(a, 1);
    a += __shfl_xor(a, 2);
    a += __shfl_xor(a, 4);
    if (kq == 0) out[(bg0 + bl) * Osz + o] = a + fcb[o];
  }
}

extern "C" void kernel_launch(void* const* d_in, const int* in_sizes, int n_in,
                              void* d_out, int out_size, void* d_ws, size_t ws_size,
                              hipStream_t stream) {
  (void)in_sizes; (void)n_in; (void)out_size; (void)ws_size;
  const float* x    = (const float*)d_in[0];
  const float* lwih = (const float*)d_in[1];
  const float* lwhh = (const float*)d_in[2];
  const float* lbih = (const float*)d_in[3];
  const float* lbhh = (const float*)d_in[4];
  const float* gwih = (const float*)d_in[5];
  const float* gwhh = (const float*)d_in[6];
  const float* gbih = (const float*)d_in[7];
  const float* gbhh = (const float*)d_in[8];
  const float* rwih = (const float*)d_in[9];
  const float* rwhh = (const float*)d_in[10];
  const float* rbih = (const float*)d_in[11];
  const float* rbhh = (const float*)d_in[12];
  const float* fcw  = (const float*)d_in[13];
  const float* fcb  = (const float*)d_in[14];
  float* outp = (float*)d_out;
  char* wsp   = (char*)d_ws;

  hipMemsetAsync(d_ws, 0, 4096, stream);  // barrier structs

  void* kargs[] = { &x, &lwih, &lwhh, &lbih, &lbhh, &gwih, &gwhh, &gbih, &gbhh,
                    &rwih, &rwhh, &rbih, &rbhh, &fcw, &fcb, &outp, &wsp };
  hipError_t e = hipLaunchCooperativeKernel((const void*)rnn_all, dim3(NWG), dim3(NTH),
                                            kargs, 0, stream);
  if (e != hipSuccess) {
    // fallback: plain launch (1 WG/CU by resource usage; groups only need their 32 WGs resident)
    rnn_all<<<dim3(NWG), dim3(NTH), 0, stream>>>(
        x, lwih, lwhh, lbih, lbhh, gwih, gwhh, gbih, gbhh,
        rwih, rwhh, rbih, rbhh, fcw, fcb, outp, wsp);
  }
}

// Round 2
// 4635.509 us; speedup vs baseline: 2.7380x; 2.7380x over previous
//
#include <hip/hip_runtime.h>
#include <cstdint>

typedef _Float16 f16;
typedef _Float16 f16x8 __attribute__((ext_vector_type(8)));
typedef float f32x4 __attribute__((ext_vector_type(4)));
typedef unsigned u32;

#define DI static __device__ __forceinline__

constexpr int T = 512, H = 512, Osz = 10;
constexpr int NWG = 256, NTH = 768;      // 12 waves per WG, 1 WG/CU
constexpr int GW = 32;                   // WGs per batch-group
constexpr int GB = 8;                    // batch rows per group
constexpr int BH = 64 * H;               // f16 elements per h-buffer parity

struct __align__(256) GSync { unsigned cnt[2]; unsigned epoch; unsigned pad[61]; };

union F16x2 { u32 u; f16 h[2]; };

DI float sigf(float x)   { return 1.f / (1.f + __expf(-x)); }
DI float tanhf_(float x) { return 1.f - 2.f / (__expf(2.f * x) + 1.f); }

DI f16x8 cvt8(const float* p) {
  f16x8 r;
#pragma unroll
  for (int j = 0; j < 8; ++j) r[j] = (f16)p[j];
  return r;
}

// Coherent (LLC-point) 16B loads, batched pair with a single waitcnt.
DI void ld2_cc(const void* p0, const void* p1, f16x8& a, f16x8& b) {
  asm volatile(
    "global_load_dwordx4 %0, %2, off sc0 sc1\n\t"
    "global_load_dwordx4 %1, %3, off sc0 sc1\n\t"
    "s_waitcnt vmcnt(0)"
    : "=&v"(a), "=&v"(b)
    : "v"(p0), "v"(p1)
    : "memory");
}

// Coherent 4B store (write-through to coherence point).
DI void st32_cc(void* p, u32 v) {
  asm volatile("global_store_dword %0, %1, off sc0 sc1" :: "v"(p), "v"(v) : "memory");
}

DI void group_barrier(GSync* g, unsigned idx, int tid) {
  __syncthreads();                       // drains vmcnt for every wave's stores
  if (tid == 0) {
    __builtin_amdgcn_fence(__ATOMIC_RELEASE, "agent");  // wbl2 on clean L2: cheap
    unsigned old = __hip_atomic_fetch_add(&g->cnt[idx & 1], 1u,
                                          __ATOMIC_RELAXED, __HIP_MEMORY_SCOPE_AGENT);
    if (old == GW - 1) {
      __hip_atomic_store(&g->cnt[idx & 1], 0u, __ATOMIC_RELAXED, __HIP_MEMORY_SCOPE_AGENT);
      __hip_atomic_store(&g->epoch, idx + 1, __ATOMIC_RELAXED, __HIP_MEMORY_SCOPE_AGENT);
    } else {
      unsigned spins = 0;
      // relaxed poll: NO cache maintenance per iteration
      while (__hip_atomic_load(&g->epoch, __ATOMIC_RELAXED, __HIP_MEMORY_SCOPE_AGENT) < idx + 1) {
        __builtin_amdgcn_s_sleep(1);
        if (++spins > 100000u) break;    // safety valve; never trips when healthy
      }
    }
  }
  __syncthreads();
}

__global__ __launch_bounds__(NTH) void rnn_all(
    const float* __restrict__ x,
    const float* __restrict__ lwih, const float* __restrict__ lwhh,
    const float* __restrict__ lbih, const float* __restrict__ lbhh,
    const float* __restrict__ gwih, const float* __restrict__ gwhh,
    const float* __restrict__ gbih, const float* __restrict__ gbhh,
    const float* __restrict__ rwih, const float* __restrict__ rwhh,
    const float* __restrict__ rbih, const float* __restrict__ rbhh,
    const float* __restrict__ fcw, const float* __restrict__ fcb,
    float* __restrict__ out, char* __restrict__ ws)
{
  // Staged prev-parity h: 3 bufs x 8 rows x 512 f16 (16B slots XOR-swizzled by row)
  __shared__ __align__(16) u32 HSu[3 * 2048];
  __shared__ float P[12][16][20];   // padded: kills 8-way bank conflicts
  __shared__ float sb[16][11];

  const int tid  = threadIdx.x;
  const int bid  = blockIdx.x;
  const int grp  = bid & 7;
  const int w32  = bid >> 3;
  const int bg0  = grp * GB;
  const int col0 = w32 * 16;
  const int w    = tid >> 6;
  const int lane = tid & 63;
  const int ln   = lane & 15;
  const int lk   = lane >> 4;

  GSync* gs = reinterpret_cast<GSync*>(ws) + grp;
  f16* HB = reinterpret_cast<f16*>(ws + 4096);   // HL | HG | HR, each 2*BH f16

  // ---- W fragments -> registers (persist across all 514 steps) ----
  f16x8 Bw[24];
  if (w < 4) {
    const int row = w * 512 + col0 + ln;
    const float* ph  = lwhh + (size_t)row * 512 + lk * 8;
    const float* px2 = lwih + (size_t)row * 256 + lk * 8;
#pragma unroll
    for (int ks = 0; ks < 16; ++ks) Bw[ks] = cvt8(ph + ks * 32);
#pragma unroll
    for (int ks = 0; ks < 8;  ++ks) Bw[16 + ks] = cvt8(px2 + ks * 32);
  } else if (w < 7) {
    const int row = (w - 4) * 512 + col0 + ln;
    const float* p = gwih + (size_t)row * 512 + lk * 8;
#pragma unroll
    for (int ks = 0; ks < 16; ++ks) Bw[ks] = cvt8(p + ks * 32);
  } else if (w < 10) {
    const int row = (w - 7) * 512 + col0 + ln;
    const float* p = gwhh + (size_t)row * 512 + lk * 8;
#pragma unroll
    for (int ks = 0; ks < 16; ++ks) Bw[ks] = cvt8(p + ks * 32);
  } else if (w == 10) {
    const float* p = rwhh + (size_t)(col0 + ln) * 512 + lk * 8;
#pragma unroll
    for (int ks = 0; ks < 16; ++ks) Bw[ks] = cvt8(p + ks * 32);
  } else {
    const float* p = rwih + (size_t)(col0 + ln) * 512 + lk * 8;
#pragma unroll
    for (int ks = 0; ks < 16; ++ks) Bw[ks] = cvt8(p + ks * 32);
  }

  // ---- biases -> LDS ----
  for (int i = tid; i < 16 * 11; i += NTH) {
    int c = i / 11, j = i % 11, col = col0 + c;
    float v;
    if (j < 4)       v = lbih[j * 512 + col] + lbhh[j * 512 + col];
    else if (j < 7)  v = gbih[(j - 4) * 512 + col];
    else if (j < 10) v = gbhh[(j - 7) * 512 + col];
    else             v = rbih[col] + rbhh[col];
    sb[c][j] = v;
  }

  // ---- zero this group's h-state with COHERENT stores ----
  {
    int i = w32 * NTH + tid;             // 0..24575 across the group
    if (i < 12288) {                     // 3 bufs * 2 par * 8 rows * 256 u32
      int buf = i >> 12, r = i & 4095, par = r >> 11, row = (r >> 8) & 7, cu = r & 255;
      void* p = (void*)(HB + (size_t)buf * 2 * BH + (size_t)par * BH
                           + (size_t)(bg0 + row) * H + cu * 2);
      st32_cc(p, 0u);
    }
  }

  group_barrier(gs, 0u, tid);

  float cr0 = 0.f, cr1 = 0.f;            // LSTM cell state (combine threads tid<64)

#pragma unroll 1
  for (int s = 0; s <= T + 1; ++s) {
    const int cur = s & 1, prev = cur ^ 1;
    const int sc = (s < T) ? s : (T - 1);

    // ---- STAGE: prev-parity h (3 bufs, 24KB) -> LDS via coherent loads ----
    {
      int s0 = tid, s1 = tid + NTH;      // two 16B slots per thread, 1536 total
      int b0 = s0 >> 9, r0 = s0 & 511, row0 = r0 >> 6, sr0 = r0 & 63;
      int b1 = s1 >> 9, r1 = s1 & 511, row1 = r1 >> 6, sr1 = r1 & 63;
      const f16* p0 = HB + (size_t)b0 * 2 * BH + (size_t)prev * BH
                         + (size_t)(bg0 + row0) * H + sr0 * 8;
      const f16* p1 = HB + (size_t)b1 * 2 * BH + (size_t)prev * BH
                         + (size_t)(bg0 + row1) * H + sr1 * 8;
      f16x8 va, vb;
      ld2_cc(p0, p1, va, vb);
      *reinterpret_cast<f16x8*>(&HSu[(b0 << 11) + row0 * 256 + ((sr0 ^ row0) << 2)]) = va;
      *reinterpret_cast<f16x8*>(&HSu[(b1 << 11) + row1 * 256 + ((sr1 ^ row1) << 2)]) = vb;
    }
    __syncthreads();

    // ---- MFMA phase: A-frags from swizzled LDS ----
    const int hbuf = (w < 7) ? 0 : ((w == 10) ? 2 : 1);
    const u32 rw_ = (u32)(ln & 7);
    const u32 abase = (u32)hbuf * 2048u + rw_ * 256u;

    f32x4 acc = {0.f, 0.f, 0.f, 0.f};
#pragma unroll
    for (int ks = 0; ks < 16; ++ks) {
      const f16x8 a = *reinterpret_cast<const f16x8*>(
          &HSu[abase + ((((u32)(ks * 4 + lk)) ^ rw_) << 2)]);
      acc = __builtin_amdgcn_mfma_f32_16x16x32_f16(a, Bw[ks], acc, 0, 0, 0);
    }
    if (w < 4) {  // LSTM x-projection (K=256), plain cached loads (L2 stays warm now)
      const int ab = bg0 + (ln & 7);
      const float* px = x + (size_t)ab * (T * 256) + (size_t)sc * 256 + lk * 8;
#pragma unroll
      for (int ks = 0; ks < 8; ++ks) {
        f16x8 a = cvt8(px + ks * 32);
        acc = __builtin_amdgcn_mfma_f32_16x16x32_f16(a, Bw[16 + ks], acc, 0, 0, 0);
      }
    }
    *reinterpret_cast<f32x4*>(&P[w][ln][lk * 4]) = acc;
    __syncthreads();

    // ---- combine: 64 threads, 2 columns each, fp32 gate math ----
    if (tid < 64) {
      const int cb = tid >> 3, cp = tid & 7;
      const int gcol = col0 + 2 * cp;
      const int gb = bg0 + cb;
      F16x2 hp;  // staged prev h_gru pair for (row cb, cols gcol..gcol+1)
      hp.u = HSu[2048 + cb * 256 + (((2 * w32 + (cp >> 2)) ^ cb) << 2) + (cp & 3)];

      F16x2 oL_, oG_, oR_;
      float crn[2];
#pragma unroll
      for (int c = 0; c < 2; ++c) {
        const int cc = 2 * cp + c;
        const float crold = c ? cr1 : cr0;
        float iL = sigf(P[0][cc][cb] + sb[cc][0]);
        float fL = sigf(P[1][cc][cb] + sb[cc][1]);
        float gL = tanhf_(P[2][cc][cb] + sb[cc][2]);
        float oL = sigf(P[3][cc][cb] + sb[cc][3]);
        float cn = fL * crold + iL * gL;
        float hLv = oL * tanhf_(cn);
        float xr = P[4][cc][cb] + sb[cc][4];
        float xz = P[5][cc][cb] + sb[cc][5];
        float xn = P[6][cc][cb] + sb[cc][6];
        float hr = P[7][cc][cb] + sb[cc][7];
        float hz = P[8][cc][cb] + sb[cc][8];
        float hn = P[9][cc][cb] + sb[cc][9];
        float rg = sigf(xr + hr), zg = sigf(xz + hz);
        float ng = tanhf_(xn + rg * hn);
        float hGv = (1.f - zg) * ng + zg * (float)hp.h[c];
        float hRv = tanhf_(P[10][cc][cb] + P[11][cc][cb] + sb[cc][10]);
        crn[c] = cn;
        oL_.h[c] = (f16)hLv; oG_.h[c] = (f16)hGv; oR_.h[c] = (f16)hRv;
      }
      f16* rowp = HB + (size_t)cur * BH + (size_t)gb * H + gcol;
      if (s < T)            { cr0 = crn[0]; cr1 = crn[1]; st32_cc((void*)rowp, oL_.u); }
      if (s >= 1 && s <= T) st32_cc((void*)(rowp + 2 * BH), oG_.u);
      if (s >= 2)           st32_cc((void*)(rowp + 4 * BH), oR_.u);
    }
    group_barrier(gs, (unsigned)(s + 1), tid);
  }

  // ---- FC epilogue: one WG per group; h_rnn(T-1) is HR parity 1 ----
  if (w32 == 0 && tid < 640) {
    const f16* hlast = HB + 4 * BH + BH;   // HR, parity 1
    int bo = tid >> 3, kq = tid & 7;
    int bl = bo / 10, o = bo % 10;
    const f16* ph = hlast + (size_t)(bg0 + bl) * H + kq * 64;
    const float* pw = fcw + (size_t)o * H + kq * 64;
    f16x8 v0, v1, v2, v3, v4, v5, v6, v7;
    ld2_cc(ph,      ph + 16, v0, v1);
    ld2_cc(ph + 32, ph + 48, v2, v3);
    // second half
    ld2_cc(ph + 32 + 32, ph + 48 + 32, v4, v5);  // placeholder ordering fixed below
    ld2_cc(ph + 48 + 48, ph + 48 + 48, v6, v7);  // (overwritten properly below)
    // NOTE: redo cleanly to avoid aliasing mistakes:
    ld2_cc(ph + 0,  ph + 8,  v0, v1);
    ld2_cc(ph + 16, ph + 24, v2, v3);
    ld2_cc(ph + 32, ph + 40, v4, v5);
    ld2_cc(ph + 48, ph + 56, v6, v7);
    float a = 0.f;
#pragma unroll
    for (int j = 0; j < 8; ++j) {
      a += (float)v0[j] * pw[0 * 8 + j];
      a += (float)v1[j] * pw[1 * 8 + j];
      a += (float)v2[j] * pw[2 * 8 + j];
      a += (float)v3[j] * pw[3 * 8 + j];
      a += (float)v4[j] * pw[4 * 8 + j];
      a += (float)v5[j] * pw[5 * 8 + j];
      a += (float)v6[j] * pw[6 * 8 + j];
      a += (float)v7[j] * pw[7 * 8 + j];
    }
    a += __shfl_xor(a, 1);
    a += __shfl_xor(a, 2);
    a += __shfl_xor(a, 4);
    if (kq == 0) out[(bg0 + bl) * Osz + o] = a + fcb[o];
  }
}

extern "C" void kernel_launch(void* const* d_in, const int* in_sizes, int n_in,
                              void* d_out, int out_size, void* d_ws, size_t ws_size,
                              hipStream_t stream) {
  (void)in_sizes; (void)n_in; (void)out_size; (void)ws_size;
  const float* x    = (const float*)d_in[0];
  const float* lwih = (const float*)d_in[1];
  const float* lwhh = (const float*)d_in[2];
  const float* lbih = (const float*)d_in[3];
  const float* lbhh = (const float*)d_in[4];
  const float* gwih = (const float*)d_in[5];
  const float* gwhh = (const float*)d_in[6];
  const float* gbih = (const float*)d_in[7];
  const float* gbhh = (const float*)d_in[8];
  const float* rwih = (const float*)d_in[9];
  const float* rwhh = (const float*)d_in[10];
  const float* rbih = (const float*)d_in[11];
  const float* rbhh = (const float*)d_in[12];
  const float* fcw  = (const float*)d_in[13];
  const float* fcb  = (const float*)d_in[14];
  float* outp = (float*)d_out;
  char* wsp   = (char*)d_ws;

  hipMemsetAsync(d_ws, 0, 4096, stream);  // barrier structs

  void* kargs[] = { &x, &lwih, &lwhh, &lbih, &lbhh, &gwih, &gwhh, &gbih, &gbhh,
                    &rwih, &rwhh, &rbih, &rbhh, &fcw, &fcb, &outp, &wsp };
  hipError_t e = hipLaunchCooperativeKernel((const void*)rnn_all, dim3(NWG), dim3(NTH),
                                            kargs, 0, stream);
  if (e != hipSuccess) {
    rnn_all<<<dim3(NWG), dim3(NTH), 0, stream>>>(
        x, lwih, lwhh, lbih, lbhh, gwih, gwhh, gbih, gbhh,
        rwih, rwhh, rbih, rbhh, fcw, fcb, outp, wsp);
  }
}